// Round 9
// baseline (150.917 us; speedup 1.0000x reference)
//
#include <hip/hip_runtime.h>

#define PI_F 3.14159f

typedef _Float16 f16;
typedef __attribute__((ext_vector_type(8))) _Float16 f16x8;
typedef __attribute__((ext_vector_type(4))) _Float16 f16x4;
typedef __attribute__((ext_vector_type(4))) float f32x4;

#define AS1 __attribute__((address_space(1)))
#define AS3 __attribute__((address_space(3)))

__device__ __forceinline__ float fast_tanh(float x) {
    const float xc = fminf(fmaxf(x, -10.f), 10.f);
    const float t  = __expf(2.f * xc);
    return (t - 1.f) * __builtin_amdgcn_rcpf(t + 1.f);
}

// ---------------------------------------------------------------------------
// convert: X fp32 -> Xh fp16
// ---------------------------------------------------------------------------
__global__ __launch_bounds__(256)
void convert_kernel(const float* __restrict__ X, f16* __restrict__ Xh)
{
    const size_t i = ((size_t)blockIdx.x * 256 + threadIdx.x) * 8;
    const float4 a = *(const float4*)(X + i);
    const float4 b = *(const float4*)(X + i + 4);
    f16x8 v;
    v[0]=(f16)a.x; v[1]=(f16)a.y; v[2]=(f16)a.z; v[3]=(f16)a.w;
    v[4]=(f16)b.x; v[5]=(f16)b.y; v[6]=(f16)b.z; v[7]=(f16)b.w;
    *(f16x8*)(Xh + i) = v;
}

// ---------------------------------------------------------------------------
// prep: Wt[1024][2048] fp16 head-organized (64 heads x 16 padded cols, pads 0)
// + bh[1024] f32. LDS-transposed: coalesced on both global sides.
// ---------------------------------------------------------------------------
__global__ void prep_kernel(const float* __restrict__ W_syn, const float* __restrict__ b_syn,
                            const float* __restrict__ W_sem, const float* __restrict__ b_sem,
                            const float* __restrict__ W_nar, const float* __restrict__ b_nar,
                            f16* __restrict__ Wt, float* __restrict__ bh)
{
    __shared__ float tile[16][65];
    const int blk = blockIdx.x;                  // 0..2047
    const int h = blk >> 5, k0 = (blk & 31) * 64;
    const float* W; const float* bb; int ld, base, width;
    if (h < 10)      { W = W_syn; bb = b_syn; ld = 100; base = h*10;      width = 10; }
    else if (h < 40) { W = W_sem; bb = b_sem; ld = 450; base = (h-10)*15; width = 15; }
    else             { W = W_nar; bb = b_nar; ld = 360; base = (h-40)*15; width = 15; }
    const int tid = threadIdx.x;
    {
        const int c = tid & 15, kr = tid >> 4;
        if (c < width)
#pragma unroll
            for (int ii = 0; ii < 4; ++ii)
                tile[c][kr + ii*16] = W[(size_t)(k0 + kr + ii*16) * ld + base + c];
    }
    __syncthreads();
    {
        const int c = tid >> 4, kq = (tid & 15) * 4;
        f16x4 v;
#pragma unroll
        for (int q = 0; q < 4; ++q)
            v[q] = (c < width) ? (f16)tile[c][kq + q] : (f16)0.0f;
        *(f16x4*)(Wt + (size_t)(h*16 + c) * 2048 + k0 + kq) = v;
    }
    if ((blk & 31) == 0 && tid < 16)
        bh[h*16 + tid] = (tid < width) ? bb[base + tid] : 0.0f;
}

// ---------------------------------------------------------------------------
// FAST PATH gemm: 256x256 tile, BK=64, 8 waves, double-buffered with COUNTED
// vmcnt (T4): STAGE(next) -> vmcnt(8) [prev tile's loads only] -> barrier ->
// COMPUTE(cur) -> barrier. Next-tile loads stay in flight across the entire
// compute phase; vmcnt never drains to 0 in the main loop.
// ---------------------------------------------------------------------------
__global__ __launch_bounds__(512, 2)
void gemm256_kernel(const f16* __restrict__ Xh, const f16* __restrict__ Wt,
                    const float* __restrict__ bh, float* __restrict__ Out)
{
    __shared__ __align__(16) char smem[131072];   // [buf:65536][A:32768|B:32768]
    const int tid  = threadIdx.x;
    // XCD-chunked bijective swizzle (nwg=256 % 8 == 0)
    const int sw   = (blockIdx.x & 7) * 32 + (blockIdx.x >> 3);
    const int bm   = sw >> 2, bn = sw & 3;
    const int m0   = bm * 256, n0 = bn * 256;
    const int wave = tid >> 6, lane = tid & 63;
    const int wm   = wave >> 2, wn = wave & 3;
    const int wrow = wm * 128, wcol = wn * 64;    // per-wave 128x64 output
    const int l15  = lane & 15, l4 = lane >> 4;

    // staging sources, granule-swizzled: LDS chunk c holds global slot (c&7)^(r&7)
    const f16* srcA[4]; const f16* srcB[4];
#pragma unroll
    for (int i = 0; i < 4; ++i) {
        const int c = i * 512 + tid;              // 0..2047
        const int r = c >> 3, j = c & 7;
        srcA[i] = Xh + (size_t)(m0 + r) * 2048 + ((j ^ (r & 7)) << 3);
        srcB[i] = Wt + (size_t)(n0 + r) * 2048 + ((j ^ (r & 7)) << 3);
    }

    f32x4 acc[8][4] = {};

#define STAGE(DBUF, KT) do {                                                    \
    const int ko_ = (KT) * 64;                                                  \
    const int ab_ = (DBUF) * 65536;                                             \
    _Pragma("unroll")                                                           \
    for (int i_ = 0; i_ < 4; ++i_)                                              \
        __builtin_amdgcn_global_load_lds((const AS1 void*)(srcA[i_] + ko_),     \
            (AS3 void*)(smem + ab_ + i_*8192 + tid*16), 16, 0, 0);              \
    _Pragma("unroll")                                                           \
    for (int i_ = 0; i_ < 4; ++i_)                                              \
        __builtin_amdgcn_global_load_lds((const AS1 void*)(srcB[i_] + ko_),     \
            (AS3 void*)(smem + ab_ + 32768 + i_*8192 + tid*16), 16, 0, 0);      \
} while (0)

#define COMPUTE(DBUF) do {                                                      \
    const int bs_ = (DBUF) * 65536;                                             \
    _Pragma("unroll")                                                           \
    for (int ks_ = 0; ks_ < 2; ++ks_) {                                         \
        f16x8 af_[8], bf_[4];                                                   \
        _Pragma("unroll")                                                       \
        for (int mf_ = 0; mf_ < 8; ++mf_) {                                     \
            const int r_ = wrow + mf_*16 + l15;                                 \
            const int g_ = (ks_*4 + l4) ^ (r_ & 7);                             \
            af_[mf_] = *(const f16x8*)(smem + bs_ + r_*128 + g_*16);            \
        }                                                                       \
        _Pragma("unroll")                                                       \
        for (int nf_ = 0; nf_ < 4; ++nf_) {                                     \
            const int r_ = wcol + nf_*16 + l15;                                 \
            const int g_ = (ks_*4 + l4) ^ (r_ & 7);                             \
            bf_[nf_] = *(const f16x8*)(smem + bs_ + 32768 + r_*128 + g_*16);    \
        }                                                                       \
        _Pragma("unroll")                                                       \
        for (int mf_ = 0; mf_ < 8; ++mf_)                                       \
            _Pragma("unroll")                                                   \
            for (int nf_ = 0; nf_ < 4; ++nf_)                                   \
                acc[mf_][nf_] = __builtin_amdgcn_mfma_f32_16x16x32_f16(         \
                    af_[mf_], bf_[nf_], acc[mf_][nf_], 0, 0, 0);                \
    }                                                                           \
} while (0)

    STAGE(0, 0);
    asm volatile("s_waitcnt vmcnt(0)" ::: "memory");   // prologue drain (once)
    __builtin_amdgcn_s_barrier();
    for (int t = 0; t < 32; ++t) {
        const int d = t & 1;
        if (t < 31) {
            STAGE(d ^ 1, t + 1);                       // 8 more in flight (16 total)
            asm volatile("s_waitcnt vmcnt(8)" ::: "memory");  // wait tile-t's 8 only
        } else {
            asm volatile("s_waitcnt vmcnt(0)" ::: "memory");
        }
        __builtin_amdgcn_s_barrier();                  // tile-t visible block-wide
        __builtin_amdgcn_s_setprio(1);
        COMPUTE(d);                                    // next-tile loads in flight
        __builtin_amdgcn_s_setprio(0);
        __builtin_amdgcn_s_barrier();                  // reads done before overwrite
    }
#undef STAGE
#undef COMPUTE

    // ---- acc -> Cs [256][256] f16, granule-swizzled G = (col>>3)^(R&31) ----
    f16* Cs = (f16*)smem;
#pragma unroll
    for (int mf = 0; mf < 8; ++mf)
#pragma unroll
        for (int nf = 0; nf < 4; ++nf)
#pragma unroll
            for (int r = 0; r < 4; ++r) {
                const int R   = wrow + mf*16 + l4*4 + r;
                const int col = wcol + nf*16 + l15;
                const int G   = (col >> 3) ^ (R & 31);
                Cs[R*256 + G*8 + (col & 7)] = (f16)acc[mf][nf][r];
            }
    __syncthreads();

    // ---- fused epilogue: 8 (token,head) pairs per thread ----
#pragma unroll
    for (int p = 0; p < 8; ++p) {
        const int linear = p * 512 + tid;         // 0..4095
        const int t  = linear >> 4;               // token-in-tile 0..255
        const int hh = linear & 15;               // head-in-tile 0..15
        const int H  = bn * 16 + hh;              // global head 0..63
        const int g0 = (2*hh)     ^ (t & 31);
        const int g1 = (2*hh + 1) ^ (t & 31);
        f16x8 y0 = *(const f16x8*)(Cs + t*256 + g0*8);
        f16x8 y1 = *(const f16x8*)(Cs + t*256 + g1*8);
        const float* bb = bh + H * 16;

        float Bv[16];
#pragma unroll
        for (int j = 0; j < 8; ++j) {
            Bv[j]     = fast_tanh((float)y0[j] + bb[j])     * PI_F;
            Bv[j + 8] = fast_tanh((float)y1[j] + bb[j + 8]) * PI_F;
        }
        float s2 = 0.f;
#pragma unroll
        for (int j = 0; j < 16; ++j) s2 += Bv[j] * Bv[j];
        const float theta = 0.5f * sqrtf(s2);
        const float sinc  = (theta > 1e-8f) ? (__sinf(theta) / theta) : 1.0f;
        const float cs    = __cosf(theta);
        const float scale = -0.5f * sinc;
        float C[16];
#pragma unroll
        for (int j = 0; j < 16; ++j) C[j] = Bv[j] * scale;

        float4 v0 = {0,0,0,0}, v1 = {0,0,0,0}, v2 = {0,0,0,0}, v3 = {0,0,0,0};
        float4 v4 = {0,0,0,0}, v5 = {0,0,0,0}, v6 = {0,0,0,0}, v7 = {0,0,0,0};
        v0.x = cs;
        if (H < 10) {                              // syn: biv 6..15
            v1.z=C[0]; v1.w=C[1];
            v2.x=C[2]; v2.y=C[3]; v2.z=C[4]; v2.w=C[5];
            v3.x=C[6]; v3.y=C[7]; v3.z=C[8]; v3.w=C[9];
        } else if (H < 40) {                       // sem: vec 1..5 + biv 6..15
            v0.y=C[0]; v0.z=C[1]; v0.w=C[2];
            v1.x=C[3]; v1.y=C[4]; v1.z=C[5]; v1.w=C[6];
            v2.x=C[7]; v2.y=C[8]; v2.z=C[9]; v2.w=C[10];
            v3.x=C[11]; v3.y=C[12]; v3.z=C[13]; v3.w=C[14];
        } else {                                   // nar: biv 6..15 + quad 26..30
            v1.z=C[0]; v1.w=C[1];
            v2.x=C[2]; v2.y=C[3]; v2.z=C[4]; v2.w=C[5];
            v3.x=C[6]; v3.y=C[7]; v3.z=C[8]; v3.w=C[9];
            v6.z=C[10]; v6.w=C[11];
            v7.x=C[12]; v7.y=C[13]; v7.z=C[14];
        }
        float4* dst = (float4*)(Out + ((size_t)(m0 + t) * 64 + H) * 32);
        dst[0]=v0; dst[1]=v1; dst[2]=v2; dst[3]=v3;
        dst[4]=v4; dst[5]=v5; dst[6]=v6; dst[7]=v7;
    }
}

// ---------------------------------------------------------------------------
// FALLBACK gemm (R5 structure): fp32 A via global_load_lds, cvt at read.
// ---------------------------------------------------------------------------
__global__ __launch_bounds__(256)
void gemm_f32a_kernel(const float* __restrict__ X, const f16* __restrict__ Wt,
                      const float* __restrict__ bh, float* __restrict__ Out)
{
    __shared__ __align__(16) char smem[49152];
    float* Asf = (float*)smem;
    f16*   Bsh = (f16*)(smem + 32768);

    const int tid  = threadIdx.x;
    const int sw   = (blockIdx.x & 7) * 128 + (blockIdx.x >> 3);
    const int bm   = sw >> 3, bn = sw & 7;
    const int m0   = bm * 128, n0 = bn * 128;
    const int wave = tid >> 6, lane = tid & 63;
    const int wr   = (wave >> 1) * 64, wc = (wave & 1) * 64;
    const int l15  = lane & 15, l4 = lane >> 4;

    f32x4 acc[4][4] = {};

    for (int kt = 0; kt < 32; ++kt) {
        const int kof = kt * 64;
#pragma unroll
        for (int i = 0; i < 8; ++i) {
            const int ac = (wave*8 + i)*64 + lane;
            const int ar = ac >> 4;
            const int agc = (ac & 15) ^ (ar & 15);
            const float* src = X + (size_t)(m0 + ar) * 2048 + kof + agc * 4;
            __builtin_amdgcn_global_load_lds((const AS1 void*)src,
                (AS3 void*)(smem + (wave*8 + i) * 1024), 16, 0, 0);
        }
#pragma unroll
        for (int i = 0; i < 4; ++i) {
            const int bc = (wave*4 + i)*64 + lane;
            const int br = bc >> 3;
            const int bgc = (bc & 7) ^ (br & 7);
            const f16* src = Wt + (size_t)(n0 + br) * 2048 + kof + bgc * 8;
            __builtin_amdgcn_global_load_lds((const AS1 void*)src,
                (AS3 void*)(smem + 32768 + (wave*4 + i) * 1024), 16, 0, 0);
        }
        __syncthreads();
#pragma unroll
        for (int ks = 0; ks < 2; ++ks) {
            f16x8 af[4], bf[4];
#pragma unroll
            for (int mf = 0; mf < 4; ++mf) {
                const int r  = wr + mf*16 + l15;
                const int s  = r & 15;
                const float4 lo = *(const float4*)(Asf + ((size_t)r*16 + ((ks*8 + l4*2)     ^ s)) * 4);
                const float4 hi = *(const float4*)(Asf + ((size_t)r*16 + ((ks*8 + l4*2 + 1) ^ s)) * 4);
                f16x8 a;
                a[0]=(f16)lo.x; a[1]=(f16)lo.y; a[2]=(f16)lo.z; a[3]=(f16)lo.w;
                a[4]=(f16)hi.x; a[5]=(f16)hi.y; a[6]=(f16)hi.z; a[7]=(f16)hi.w;
                af[mf] = a;
            }
#pragma unroll
            for (int nf = 0; nf < 4; ++nf) {
                const int r = wc + nf*16 + l15;
                bf[nf] = *(const f16x8*)(Bsh + ((size_t)r*8 + ((ks*4 + l4) ^ (r & 7))) * 8);
            }
#pragma unroll
            for (int mf = 0; mf < 4; ++mf)
#pragma unroll
                for (int nf = 0; nf < 4; ++nf)
                    acc[mf][nf] = __builtin_amdgcn_mfma_f32_16x16x32_f16(af[mf], bf[nf], acc[mf][nf], 0, 0, 0);
        }
        __syncthreads();
    }

    f16* Cs = (f16*)smem;
#pragma unroll
    for (int mf = 0; mf < 4; ++mf)
#pragma unroll
        for (int nf = 0; nf < 4; ++nf)
#pragma unroll
            for (int r = 0; r < 4; ++r) {
                const int R = wr + mf*16 + l4*4 + r;
                const int col = wc + nf*16 + l15;
                const int G = (col >> 3) ^ (R & 15);
                Cs[R*128 + G*8 + (col & 7)] = (f16)acc[mf][nf][r];
            }
    __syncthreads();
#pragma unroll
    for (int p = 0; p < 4; ++p) {
        const int linear = p * 256 + tid;
        const int t  = linear >> 3;
        const int hh = linear & 7;
        const int H  = bn * 8 + hh;
        const int g0 = (2*hh)     ^ (t & 15);
        const int g1 = (2*hh + 1) ^ (t & 15);
        f16x8 y0 = *(const f16x8*)(Cs + t*128 + g0*8);
        f16x8 y1 = *(const f16x8*)(Cs + t*128 + g1*8);
        const float* bb = bh + H * 16;
        float Bv[16];
#pragma unroll
        for (int j = 0; j < 8; ++j) {
            Bv[j]     = fast_tanh((float)y0[j] + bb[j])     * PI_F;
            Bv[j + 8] = fast_tanh((float)y1[j] + bb[j + 8]) * PI_F;
        }
        float s2 = 0.f;
#pragma unroll
        for (int j = 0; j < 16; ++j) s2 += Bv[j] * Bv[j];
        const float theta = 0.5f * sqrtf(s2);
        const float sinc  = (theta > 1e-8f) ? (__sinf(theta) / theta) : 1.0f;
        const float cs    = __cosf(theta);
        const float scale = -0.5f * sinc;
        float C[16];
#pragma unroll
        for (int j = 0; j < 16; ++j) C[j] = Bv[j] * scale;
        float4 v0 = {0,0,0,0}, v1 = {0,0,0,0}, v2 = {0,0,0,0}, v3 = {0,0,0,0};
        float4 v4 = {0,0,0,0}, v5 = {0,0,0,0}, v6 = {0,0,0,0}, v7 = {0,0,0,0};
        v0.x = cs;
        if (H < 10) {
            v1.z=C[0]; v1.w=C[1];
            v2.x=C[2]; v2.y=C[3]; v2.z=C[4]; v2.w=C[5];
            v3.x=C[6]; v3.y=C[7]; v3.z=C[8]; v3.w=C[9];
        } else if (H < 40) {
            v0.y=C[0]; v0.z=C[1]; v0.w=C[2];
            v1.x=C[3]; v1.y=C[4]; v1.z=C[5]; v1.w=C[6];
            v2.x=C[7]; v2.y=C[8]; v2.z=C[9]; v2.w=C[10];
            v3.x=C[11]; v3.y=C[12]; v3.z=C[13]; v3.w=C[14];
        } else {
            v1.z=C[0]; v1.w=C[1];
            v2.x=C[2]; v2.y=C[3]; v2.z=C[4]; v2.w=C[5];
            v3.x=C[6]; v3.y=C[7]; v3.z=C[8]; v3.w=C[9];
            v6.z=C[10]; v6.w=C[11];
            v7.x=C[12]; v7.y=C[13]; v7.z=C[14];
        }
        float4* dst = (float4*)(Out + ((size_t)(m0 + t) * 64 + H) * 32);
        dst[0]=v0; dst[1]=v1; dst[2]=v2; dst[3]=v3;
        dst[4]=v4; dst[5]=v5; dst[6]=v6; dst[7]=v7;
    }
}

// ---------------------------------------------------------------------------
extern "C" void kernel_launch(void* const* d_in, const int* in_sizes, int n_in,
                              void* d_out, int out_size, void* d_ws, size_t ws_size,
                              hipStream_t stream)
{
    const float* x     = (const float*)d_in[0];
    const float* W_syn = (const float*)d_in[1];
    const float* b_syn = (const float*)d_in[2];
    const float* W_sem = (const float*)d_in[3];
    const float* b_sem = (const float*)d_in[4];
    const float* W_nar = (const float*)d_in[5];
    const float* b_nar = (const float*)d_in[6];

    // ws layout: Wt fp16 4MB | bh f32 (64KB slot) | Xh fp16 64MB
    const size_t WT_B = (size_t)4*1024*1024, BH_B = 65536;
    const size_t XH_B = (size_t)33554432 * 2;
    f16*   Wt = (f16*)d_ws;
    float* bh = (float*)((char*)d_ws + WT_B);
    f16*   Xh = (f16*)((char*)d_ws + WT_B + BH_B);
    float* Out = (float*)d_out;

    prep_kernel<<<2048, 256, 0, stream>>>(W_syn, b_syn, W_sem, b_sem, W_nar, b_nar, Wt, bh);
    if (ws_size >= WT_B + BH_B + XH_B) {
        convert_kernel<<<16384, 256, 0, stream>>>(x, Xh);
        gemm256_kernel<<<256, 512, 0, stream>>>(Xh, Wt, bh, Out);
    } else {
        gemm_f32a_kernel<<<1024, 256, 0, stream>>>(x, Wt, bh, Out);
    }
}

// Round 10
// 149.406 us; speedup vs baseline: 1.0101x; 1.0101x over previous
//
#include <hip/hip_runtime.h>

#define PI_F 3.14159f

typedef _Float16 f16;
typedef __attribute__((ext_vector_type(8))) _Float16 f16x8;
typedef __attribute__((ext_vector_type(4))) _Float16 f16x4;
typedef __attribute__((ext_vector_type(4))) float f32x4;

#define AS1 __attribute__((address_space(1)))
#define AS3 __attribute__((address_space(3)))

__device__ __forceinline__ float fast_tanh(float x) {
    const float xc = fminf(fmaxf(x, -10.f), 10.f);
    const float t  = __expf(2.f * xc);
    return (t - 1.f) * __builtin_amdgcn_rcpf(t + 1.f);
}

// ---------------------------------------------------------------------------
// convert: X fp32 -> Xh fp16
// ---------------------------------------------------------------------------
__global__ __launch_bounds__(256)
void convert_kernel(const float* __restrict__ X, f16* __restrict__ Xh)
{
    const size_t i = ((size_t)blockIdx.x * 256 + threadIdx.x) * 8;
    const float4 a = *(const float4*)(X + i);
    const float4 b = *(const float4*)(X + i + 4);
    f16x8 v;
    v[0]=(f16)a.x; v[1]=(f16)a.y; v[2]=(f16)a.z; v[3]=(f16)a.w;
    v[4]=(f16)b.x; v[5]=(f16)b.y; v[6]=(f16)b.z; v[7]=(f16)b.w;
    *(f16x8*)(Xh + i) = v;
}

// ---------------------------------------------------------------------------
// prep: Wt[1024][2048] fp16 head-organized (64 heads x 16 padded cols, pads 0)
// + bh[1024] f32. LDS-transposed: coalesced on both global sides.
// ---------------------------------------------------------------------------
__global__ void prep_kernel(const float* __restrict__ W_syn, const float* __restrict__ b_syn,
                            const float* __restrict__ W_sem, const float* __restrict__ b_sem,
                            const float* __restrict__ W_nar, const float* __restrict__ b_nar,
                            f16* __restrict__ Wt, float* __restrict__ bh)
{
    __shared__ float tile[16][65];
    const int blk = blockIdx.x;                  // 0..2047
    const int h = blk >> 5, k0 = (blk & 31) * 64;
    const float* W; const float* bb; int ld, base, width;
    if (h < 10)      { W = W_syn; bb = b_syn; ld = 100; base = h*10;      width = 10; }
    else if (h < 40) { W = W_sem; bb = b_sem; ld = 450; base = (h-10)*15; width = 15; }
    else             { W = W_nar; bb = b_nar; ld = 360; base = (h-40)*15; width = 15; }
    const int tid = threadIdx.x;
    {
        const int c = tid & 15, kr = tid >> 4;
        if (c < width)
#pragma unroll
            for (int ii = 0; ii < 4; ++ii)
                tile[c][kr + ii*16] = W[(size_t)(k0 + kr + ii*16) * ld + base + c];
    }
    __syncthreads();
    {
        const int c = tid >> 4, kq = (tid & 15) * 4;
        f16x4 v;
#pragma unroll
        for (int q = 0; q < 4; ++q)
            v[q] = (c < width) ? (f16)tile[c][kq + q] : (f16)0.0f;
        *(f16x4*)(Wt + (size_t)(h*16 + c) * 2048 + k0 + kq) = v;
    }
    if ((blk & 31) == 0 && tid < 16)
        bh[h*16 + tid] = (tid < width) ? bb[base + tid] : 0.0f;
}

// ---------------------------------------------------------------------------
// FAST PATH gemm: 256x256, BK=64, 8 waves, m201-style 8-phase schedule.
// LDS: A0@0 | B0@32768 | A1@65536 | B1@98304 (even kt -> buf0, odd -> buf1).
// Per phase: {stage 1 half-tile (2 gll) ; ds_read quad ; [vmcnt p3/p7] ;
//             barrier ; lgkmcnt(0) ; setprio(1) ; 16 MFMA ; setprio(0) ; barrier}
// vmcnt(2) drains exactly the K-tile consumed next; never 0 in steady state.
// ---------------------------------------------------------------------------
__global__ __launch_bounds__(512, 2)
void gemm256_kernel(const f16* __restrict__ Xh, const f16* __restrict__ Wt,
                    const float* __restrict__ bh, float* __restrict__ Out)
{
    __shared__ __align__(16) char smem[131072];
    const int tid  = threadIdx.x;
    const int sw   = (blockIdx.x & 7) * 32 + (blockIdx.x >> 3);   // XCD-chunked
    const int bm   = sw >> 2, bn = sw & 3;
    const int m0   = bm * 256, n0 = bn * 256;
    const int wave = tid >> 6, lane = tid & 63;
    const int wm   = wave >> 2, wn = wave & 3;
    const int wrow = wm * 128, wcol = wn * 64;
    const int l15  = lane & 15, l4 = lane >> 4;
    const int sa   = l15 & 7;

    // fragment ds_read byte offsets (granule swizzle g = (ks*4+l4)^(row&7))
    const int aOff0 = (wrow + l15) * 128 + ((l4     ^ sa) << 4);
    const int aOff1 = (wrow + l15) * 128 + (((4|l4) ^ sa) << 4);
    const int bOff0 = (wcol + l15) * 128 + ((l4     ^ sa) << 4);
    const int bOff1 = (wcol + l15) * 128 + (((4|l4) ^ sa) << 4);

    // staging sources (R8-validated): chunk c = i*512+tid -> row r=c>>3, slot j=c&7
    const f16* srcA[4]; const f16* srcB[4];
#pragma unroll
    for (int i = 0; i < 4; ++i) {
        const int c = i * 512 + tid;
        const int r = c >> 3, j = c & 7;
        srcA[i] = Xh + (size_t)(m0 + r) * 2048 + ((j ^ (r & 7)) << 3);
        srcB[i] = Wt + (size_t)(n0 + r) * 2048 + ((j ^ (r & 7)) << 3);
    }

    f32x4 acc[8][4] = {};
    f16x8 aF[4][2], bLo[2][2], bHi[2][2];

#define GLL(SRC, DOFF) __builtin_amdgcn_global_load_lds(                        \
        (const AS1 void*)(SRC), (AS3 void*)(smem + (DOFF) + tid*16), 16, 0, 0)
#define STAGE_HALF(P0, P1, DOFF, KT) do {                                       \
        GLL((P0) + (KT)*64, (DOFF)); GLL((P1) + (KT)*64, (DOFF) + 8192); } while (0)

#define RD_ALO(BUF) { _Pragma("unroll") for (int m_=0;m_<4;++m_){               \
        aF[m_][0] = *(const f16x8*)(smem + (BUF) + aOff0 + m_*2048);            \
        aF[m_][1] = *(const f16x8*)(smem + (BUF) + aOff1 + m_*2048); } }
#define RD_AHI(BUF) { _Pragma("unroll") for (int m_=0;m_<4;++m_){               \
        aF[m_][0] = *(const f16x8*)(smem + (BUF) + aOff0 + (m_+4)*2048);        \
        aF[m_][1] = *(const f16x8*)(smem + (BUF) + aOff1 + (m_+4)*2048); } }
#define RD_BLO(BUF) { _Pragma("unroll") for (int n_=0;n_<2;++n_){               \
        bLo[n_][0] = *(const f16x8*)(smem + 32768 + (BUF) + bOff0 + n_*2048);   \
        bLo[n_][1] = *(const f16x8*)(smem + 32768 + (BUF) + bOff1 + n_*2048); } }
#define RD_BHI(BUF) { _Pragma("unroll") for (int n_=0;n_<2;++n_){               \
        bHi[n_][0] = *(const f16x8*)(smem + 32768 + (BUF) + bOff0 + (n_+2)*2048); \
        bHi[n_][1] = *(const f16x8*)(smem + 32768 + (BUF) + bOff1 + (n_+2)*2048); } }

#define MIDBAR() do { __builtin_amdgcn_s_barrier();                             \
        asm volatile("s_waitcnt lgkmcnt(0)" ::: "memory");                      \
        __builtin_amdgcn_sched_barrier(0); } while (0)

#define MFMA16(MB, NB, BF)                                                      \
    { _Pragma("unroll") for (int m_=0;m_<4;++m_)                                \
      _Pragma("unroll") for (int n_=0;n_<2;++n_)                                \
      _Pragma("unroll") for (int k_=0;k_<2;++k_)                                \
        acc[(MB)+m_][(NB)+n_] = __builtin_amdgcn_mfma_f32_16x16x32_f16(         \
            aF[m_][k_], BF[n_][k_], acc[(MB)+m_][(NB)+n_], 0, 0, 0); }

#define PHASE_TAIL(MB, NB, BF) do {                                             \
        MIDBAR();                                                               \
        __builtin_amdgcn_s_setprio(1);                                          \
        MFMA16(MB, NB, BF);                                                     \
        __builtin_amdgcn_s_setprio(0);                                          \
        __builtin_amdgcn_s_barrier(); } while (0)

    // ---- prologue: kt0 all 4 halves + kt1 A-h0; drain kt0, leave 2 in flight
    STAGE_HALF(srcA[0], srcA[1],      0, 0);
    STAGE_HALF(srcA[2], srcA[3],  16384, 0);
    STAGE_HALF(srcB[0], srcB[1],  32768, 0);
    STAGE_HALF(srcB[2], srcB[3],  49152, 0);
    STAGE_HALF(srcA[0], srcA[1],  65536, 1);
    asm volatile("s_waitcnt vmcnt(2)" ::: "memory");
    __builtin_amdgcn_s_barrier();

#pragma unroll 1
    for (int t2 = 0; t2 < 16; ++t2) {
        const int kt1 = 2*t2 + 1;
        const bool pre = (t2 < 15);
        // p0: stage kt1 A-h1 | read buf0 A-lo + B-lo | Q0
        STAGE_HALF(srcA[2], srcA[3], 81920, kt1);
        RD_ALO(0); RD_BLO(0);
        PHASE_TAIL(0, 0, bLo);
        // p1: stage kt1 B-h0 | read buf0 B-hi | Q1
        STAGE_HALF(srcB[0], srcB[1], 98304, kt1);
        RD_BHI(0);
        PHASE_TAIL(0, 2, bHi);
        // p2: stage kt1 B-h1 | read buf0 A-hi | Q2
        STAGE_HALF(srcB[2], srcB[3], 114688, kt1);
        RD_AHI(0);
        PHASE_TAIL(4, 0, bLo);
        // p3: stage kt0+2 A-h0 | vmcnt -> kt1 confirmed | Q3
        if (pre) {
            STAGE_HALF(srcA[0], srcA[1], 0, kt1 + 1);
            asm volatile("s_waitcnt vmcnt(2)" ::: "memory");
        } else {
            asm volatile("s_waitcnt vmcnt(0)" ::: "memory");
        }
        PHASE_TAIL(4, 2, bHi);
        // p4: stage kt0+2 A-h1 | read buf1 A-lo + B-lo | Q0
        if (pre) STAGE_HALF(srcA[2], srcA[3], 16384, kt1 + 1);
        RD_ALO(65536); RD_BLO(65536);
        PHASE_TAIL(0, 0, bLo);
        // p5: stage kt0+2 B-h0 | read buf1 B-hi | Q1
        if (pre) STAGE_HALF(srcB[0], srcB[1], 32768, kt1 + 1);
        RD_BHI(65536);
        PHASE_TAIL(0, 2, bHi);
        // p6: stage kt0+2 B-h1 | read buf1 A-hi | Q2
        if (pre) STAGE_HALF(srcB[2], srcB[3], 49152, kt1 + 1);
        RD_AHI(65536);
        PHASE_TAIL(4, 0, bLo);
        // p7: stage kt1+2 A-h0 | vmcnt -> kt0+2 confirmed | Q3
        if (pre) {
            STAGE_HALF(srcA[0], srcA[1], 65536, kt1 + 2);
            asm volatile("s_waitcnt vmcnt(2)" ::: "memory");
        }
        PHASE_TAIL(4, 2, bHi);
    }
#undef GLL
#undef STAGE_HALF
#undef RD_ALO
#undef RD_AHI
#undef RD_BLO
#undef RD_BHI
#undef MIDBAR
#undef MFMA16
#undef PHASE_TAIL

    // ---- acc -> Cs [256][256] f16, granule-swizzled G = (col>>3)^(R&31) ----
    f16* Cs = (f16*)smem;
#pragma unroll
    for (int mf = 0; mf < 8; ++mf)
#pragma unroll
        for (int nf = 0; nf < 4; ++nf)
#pragma unroll
            for (int r = 0; r < 4; ++r) {
                const int R   = wrow + mf*16 + l4*4 + r;
                const int col = wcol + nf*16 + l15;
                const int G   = (col >> 3) ^ (R & 31);
                Cs[R*256 + G*8 + (col & 7)] = (f16)acc[mf][nf][r];
            }
    __syncthreads();

    // ---- fused epilogue: 8 (token,head) pairs per thread ----
#pragma unroll
    for (int p = 0; p < 8; ++p) {
        const int linear = p * 512 + tid;
        const int t  = linear >> 4;
        const int hh = linear & 15;
        const int H  = bn * 16 + hh;
        const int g0 = (2*hh)     ^ (t & 31);
        const int g1 = (2*hh + 1) ^ (t & 31);
        f16x8 y0 = *(const f16x8*)(Cs + t*256 + g0*8);
        f16x8 y1 = *(const f16x8*)(Cs + t*256 + g1*8);
        const float* bb = bh + H * 16;

        float Bv[16];
#pragma unroll
        for (int j = 0; j < 8; ++j) {
            Bv[j]     = fast_tanh((float)y0[j] + bb[j])     * PI_F;
            Bv[j + 8] = fast_tanh((float)y1[j] + bb[j + 8]) * PI_F;
        }
        float s2 = 0.f;
#pragma unroll
        for (int j = 0; j < 16; ++j) s2 += Bv[j] * Bv[j];
        const float theta = 0.5f * sqrtf(s2);
        const float sinc  = (theta > 1e-8f) ? (__sinf(theta) / theta) : 1.0f;
        const float cs    = __cosf(theta);
        const float scale = -0.5f * sinc;
        float C[16];
#pragma unroll
        for (int j = 0; j < 16; ++j) C[j] = Bv[j] * scale;

        float4 v0 = {0,0,0,0}, v1 = {0,0,0,0}, v2 = {0,0,0,0}, v3 = {0,0,0,0};
        float4 v4 = {0,0,0,0}, v5 = {0,0,0,0}, v6 = {0,0,0,0}, v7 = {0,0,0,0};
        v0.x = cs;
        if (H < 10) {                              // syn: biv 6..15
            v1.z=C[0]; v1.w=C[1];
            v2.x=C[2]; v2.y=C[3]; v2.z=C[4]; v2.w=C[5];
            v3.x=C[6]; v3.y=C[7]; v3.z=C[8]; v3.w=C[9];
        } else if (H < 40) {                       // sem: vec 1..5 + biv 6..15
            v0.y=C[0]; v0.z=C[1]; v0.w=C[2];
            v1.x=C[3]; v1.y=C[4]; v1.z=C[5]; v1.w=C[6];
            v2.x=C[7]; v2.y=C[8]; v2.z=C[9]; v2.w=C[10];
            v3.x=C[11]; v3.y=C[12]; v3.z=C[13]; v3.w=C[14];
        } else {                                   // nar: biv 6..15 + quad 26..30
            v1.z=C[0]; v1.w=C[1];
            v2.x=C[2]; v2.y=C[3]; v2.z=C[4]; v2.w=C[5];
            v3.x=C[6]; v3.y=C[7]; v3.z=C[8]; v3.w=C[9];
            v6.z=C[10]; v6.w=C[11];
            v7.x=C[12]; v7.y=C[13]; v7.z=C[14];
        }
        float4* dst = (float4*)(Out + ((size_t)(m0 + t) * 64 + H) * 32);
        dst[0]=v0; dst[1]=v1; dst[2]=v2; dst[3]=v3;
        dst[4]=v4; dst[5]=v5; dst[6]=v6; dst[7]=v7;
    }
}

// ---------------------------------------------------------------------------
// FALLBACK gemm (R5 structure): fp32 A via global_load_lds, cvt at read.
// ---------------------------------------------------------------------------
__global__ __launch_bounds__(256)
void gemm_f32a_kernel(const float* __restrict__ X, const f16* __restrict__ Wt,
                      const float* __restrict__ bh, float* __restrict__ Out)
{
    __shared__ __align__(16) char smem[49152];
    float* Asf = (float*)smem;
    f16*   Bsh = (f16*)(smem + 32768);

    const int tid  = threadIdx.x;
    const int sw   = (blockIdx.x & 7) * 128 + (blockIdx.x >> 3);
    const int bm   = sw >> 3, bn = sw & 7;
    const int m0   = bm * 128, n0 = bn * 128;
    const int wave = tid >> 6, lane = tid & 63;
    const int wr   = (wave >> 1) * 64, wc = (wave & 1) * 64;
    const int l15  = lane & 15, l4 = lane >> 4;

    f32x4 acc[4][4] = {};

    for (int kt = 0; kt < 32; ++kt) {
        const int kof = kt * 64;
#pragma unroll
        for (int i = 0; i < 8; ++i) {
            const int ac = (wave*8 + i)*64 + lane;
            const int ar = ac >> 4;
            const int agc = (ac & 15) ^ (ar & 15);
            const float* src = X + (size_t)(m0 + ar) * 2048 + kof + agc * 4;
            __builtin_amdgcn_global_load_lds((const AS1 void*)src,
                (AS3 void*)(smem + (wave*8 + i) * 1024), 16, 0, 0);
        }
#pragma unroll
        for (int i = 0; i < 4; ++i) {
            const int bc = (wave*4 + i)*64 + lane;
            const int br = bc >> 3;
            const int bgc = (bc & 7) ^ (br & 7);
            const f16* src = Wt + (size_t)(n0 + br) * 2048 + kof + bgc * 8;
            __builtin_amdgcn_global_load_lds((const AS1 void*)src,
                (AS3 void*)(smem + 32768 + (wave*4 + i) * 1024), 16, 0, 0);
        }
        __syncthreads();
#pragma unroll
        for (int ks = 0; ks < 2; ++ks) {
            f16x8 af[4], bf[4];
#pragma unroll
            for (int mf = 0; mf < 4; ++mf) {
                const int r  = wr + mf*16 + l15;
                const int s  = r & 15;
                const float4 lo = *(const float4*)(Asf + ((size_t)r*16 + ((ks*8 + l4*2)     ^ s)) * 4);
                const float4 hi = *(const float4*)(Asf + ((size_t)r*16 + ((ks*8 + l4*2 + 1) ^ s)) * 4);
                f16x8 a;
                a[0]=(f16)lo.x; a[1]=(f16)lo.y; a[2]=(f16)lo.z; a[3]=(f16)lo.w;
                a[4]=(f16)hi.x; a[5]=(f16)hi.y; a[6]=(f16)hi.z; a[7]=(f16)hi.w;
                af[mf] = a;
            }
#pragma unroll
            for (int nf = 0; nf < 4; ++nf) {
                const int r = wc + nf*16 + l15;
                bf[nf] = *(const f16x8*)(Bsh + ((size_t)r*8 + ((ks*4 + l4) ^ (r & 7))) * 8);
            }
#pragma unroll
            for (int mf = 0; mf < 4; ++mf)
#pragma unroll
                for (int nf = 0; nf < 4; ++nf)
                    acc[mf][nf] = __builtin_amdgcn_mfma_f32_16x16x32_f16(af[mf], bf[nf], acc[mf][nf], 0, 0, 0);
        }
        __syncthreads();
    }

    f16* Cs = (f16*)smem;
#pragma unroll
    for (int mf = 0; mf < 4; ++mf)
#pragma unroll
        for (int nf = 0; nf < 4; ++nf)
#pragma unroll
            for (int r = 0; r < 4; ++r) {
                const int R = wr + mf*16 + l4*4 + r;
                const int col = wc + nf*16 + l15;
                const int G = (col >> 3) ^ (R & 15);
                Cs[R*128 + G*8 + (col & 7)] = (f16)acc[mf][nf][r];
            }
    __syncthreads();
#pragma unroll
    for (int p = 0; p < 4; ++p) {
        const int linear = p * 256 + tid;
        const int t  = linear >> 3;
        const int hh = linear & 7;
        const int H  = bn * 8 + hh;
        const int g0 = (2*hh)     ^ (t & 15);
        const int g1 = (2*hh + 1) ^ (t & 15);
        f16x8 y0 = *(const f16x8*)(Cs + t*128 + g0*8);
        f16x8 y1 = *(const f16x8*)(Cs + t*128 + g1*8);
        const float* bb = bh + H * 16;
        float Bv[16];
#pragma unroll
        for (int j = 0; j < 8; ++j) {
            Bv[j]     = fast_tanh((float)y0[j] + bb[j])     * PI_F;
            Bv[j + 8] = fast_tanh((float)y1[j] + bb[j + 8]) * PI_F;
        }
        float s2 = 0.f;
#pragma unroll
        for (int j = 0; j < 16; ++j) s2 += Bv[j] * Bv[j];
        const float theta = 0.5f * sqrtf(s2);
        const float sinc  = (theta > 1e-8f) ? (__sinf(theta) / theta) : 1.0f;
        const float cs    = __cosf(theta);
        const float scale = -0.5f * sinc;
        float C[16];
#pragma unroll
        for (int j = 0; j < 16; ++j) C[j] = Bv[j] * scale;
        float4 v0 = {0,0,0,0}, v1 = {0,0,0,0}, v2 = {0,0,0,0}, v3 = {0,0,0,0};
        float4 v4 = {0,0,0,0}, v5 = {0,0,0,0}, v6 = {0,0,0,0}, v7 = {0,0,0,0};
        v0.x = cs;
        if (H < 10) {
            v1.z=C[0]; v1.w=C[1];
            v2.x=C[2]; v2.y=C[3]; v2.z=C[4]; v2.w=C[5];
            v3.x=C[6]; v3.y=C[7]; v3.z=C[8]; v3.w=C[9];
        } else if (H < 40) {
            v0.y=C[0]; v0.z=C[1]; v0.w=C[2];
            v1.x=C[3]; v1.y=C[4]; v1.z=C[5]; v1.w=C[6];
            v2.x=C[7]; v2.y=C[8]; v2.z=C[9]; v2.w=C[10];
            v3.x=C[11]; v3.y=C[12]; v3.z=C[13]; v3.w=C[14];
        } else {
            v1.z=C[0]; v1.w=C[1];
            v2.x=C[2]; v2.y=C[3]; v2.z=C[4]; v2.w=C[5];
            v3.x=C[6]; v3.y=C[7]; v3.z=C[8]; v3.w=C[9];
            v6.z=C[10]; v6.w=C[11];
            v7.x=C[12]; v7.y=C[13]; v7.z=C[14];
        }
        float4* dst = (float4*)(Out + ((size_t)(m0 + t) * 64 + H) * 32);
        dst[0]=v0; dst[1]=v1; dst[2]=v2; dst[3]=v3;
        dst[4]=v4; dst[5]=v5; dst[6]=v6; dst[7]=v7;
    }
}

// ---------------------------------------------------------------------------
extern "C" void kernel_launch(void* const* d_in, const int* in_sizes, int n_in,
                              void* d_out, int out_size, void* d_ws, size_t ws_size,
                              hipStream_t stream)
{
    const float* x     = (const float*)d_in[0];
    const float* W_syn = (const float*)d_in[1];
    const float* b_syn = (const float*)d_in[2];
    const float* W_sem = (const float*)d_in[3];
    const float* b_sem = (const float*)d_in[4];
    const float* W_nar = (const float*)d_in[5];
    const float* b_nar = (const float*)d_in[6];

    // ws layout: Wt fp16 4MB | bh f32 (64KB slot) | Xh fp16 64MB
    const size_t WT_B = (size_t)4*1024*1024, BH_B = 65536;
    const size_t XH_B = (size_t)33554432 * 2;
    f16*   Wt = (f16*)d_ws;
    float* bh = (float*)((char*)d_ws + WT_B);
    f16*   Xh = (f16*)((char*)d_ws + WT_B + BH_B);
    float* Out = (float*)d_out;

    prep_kernel<<<2048, 256, 0, stream>>>(W_syn, b_syn, W_sem, b_sem, W_nar, b_nar, Wt, bh);
    if (ws_size >= WT_B + BH_B + XH_B) {
        convert_kernel<<<16384, 256, 0, stream>>>(x, Xh);
        gemm256_kernel<<<256, 512, 0, stream>>>(Xh, Wt, bh, Out);
    } else {
        gemm_f32a_kernel<<<1024, 256, 0, stream>>>(x, Wt, bh, Out);
    }
}